// Round 1
// baseline (172.199 us; speedup 1.0000x reference)
//
#include <hip/hip_runtime.h>
#include <cstdint>
#include <cstddef>

#define BATCH 4096
#define IDIM 1024
#define ODIM 1024
#define KDIM 4096   // 4 * IDIM  (degrees 1..4; degree 0 folded into bias)

typedef __attribute__((ext_vector_type(8))) short bf16x8;
typedef __attribute__((ext_vector_type(4))) float f32x4;

__device__ __forceinline__ unsigned short f2bf(float f) {
  union { float f; unsigned int u; } v; v.f = f;
  unsigned int r = (v.u + 0x7FFFu + ((v.u >> 16) & 1u)) >> 16;  // RNE
  return (unsigned short)r;
}
__device__ __forceinline__ float bf2f(unsigned short u) {
  union { unsigned int u; float f; } v; v.u = ((unsigned int)u) << 16;
  return v.f;
}

__device__ __forceinline__ void load_lds16(const void* g, void* l) {
  __builtin_amdgcn_global_load_lds(
      (const __attribute__((address_space(1))) void*)g,
      (__attribute__((address_space(3))) void*)l, 16, 0, 0);
}

// ---------------------------------------------------------------------------
// Kernel 1: per-row LayerNorm + tanh + Chebyshev T1..T4, bf16 output.
// A[b][d2*1024 + i] = T_{d2+1}(h[b][i]),  d2 in [0,4)
// ---------------------------------------------------------------------------
__global__ __launch_bounds__(256) void prep_ln(
    const float* __restrict__ x, const float* __restrict__ lnw,
    const float* __restrict__ lnb, unsigned short* __restrict__ A) {
  int b = blockIdx.x;
  int t = threadIdx.x;
  const float4 v = ((const float4*)(x + (size_t)b * IDIM))[t];
  float s  = v.x + v.y + v.z + v.w;
  float s2 = v.x * v.x + v.y * v.y + v.z * v.z + v.w * v.w;
#pragma unroll
  for (int off = 32; off > 0; off >>= 1) {
    s  += __shfl_down(s, off);
    s2 += __shfl_down(s2, off);
  }
  __shared__ float rs[4], rq[4];
  int lane = t & 63, wv = t >> 6;
  if (lane == 0) { rs[wv] = s; rq[wv] = s2; }
  __syncthreads();
  float S1 = rs[0] + rs[1] + rs[2] + rs[3];
  float S2 = rq[0] + rq[1] + rq[2] + rq[3];
  float mean = S1 * (1.0f / IDIM);
  float var  = S2 * (1.0f / IDIM) - mean * mean;
  float rstd = rsqrtf(var + 1e-5f);

  const float4 w4 = ((const float4*)lnw)[t];
  const float4 b4 = ((const float4*)lnb)[t];
  float xs[4] = {v.x, v.y, v.z, v.w};
  float ws4[4] = {w4.x, w4.y, w4.z, w4.w};
  float bs4[4] = {b4.x, b4.y, b4.z, b4.w};

  unsigned short u1[4], u2[4], u3[4], u4[4];
#pragma unroll
  for (int j = 0; j < 4; j++) {
    float h  = tanhf((xs[j] - mean) * rstd * ws4[j] + bs4[j]);
    float T2 = 2.0f * h * h - 1.0f;
    float T3 = 2.0f * h * T2 - h;
    float T4 = 2.0f * h * T3 - T2;
    u1[j] = f2bf(h); u2[j] = f2bf(T2); u3[j] = f2bf(T3); u4[j] = f2bf(T4);
  }
  size_t base = (size_t)b * KDIM;
  *(ushort4*)(A + base + 0 * IDIM + t * 4) = *(ushort4*)u1;
  *(ushort4*)(A + base + 1 * IDIM + t * 4) = *(ushort4*)u2;
  *(ushort4*)(A + base + 2 * IDIM + t * 4) = *(ushort4*)u3;
  *(ushort4*)(A + base + 3 * IDIM + t * 4) = *(ushort4*)u4;
}

// ---------------------------------------------------------------------------
// Kernel 2: transpose coeffs C[i][o][d] -> Bt[o][d2*1024+i] (bf16, d=d2+1),
// and bias[o] = sum_i C[i][o][0] via LDS tile + atomics.
// Tile: 64 i x 64 o per block.
// ---------------------------------------------------------------------------
__global__ __launch_bounds__(256) void prep_coef(
    const float* __restrict__ C, unsigned short* __restrict__ Bt,
    float* __restrict__ bias) {
  __shared__ unsigned short lds[64 * 5 * 64];  // [oo][d][ii]
  int i0 = blockIdx.x * 64, o0 = blockIdx.y * 64;
  int t = threadIdx.x;
  // read phase: 64 rows x 320 floats (contiguous, 16B-aligned since o0%4==0)
#pragma unroll
  for (int r = 0; r < 20; r++) {
    int idx = r * 256 + t;          // 0..5119 float4s
    int ii  = idx / 80;             // 80 float4 per i-row
    int c4  = idx - ii * 80;
    const float4 f = *(const float4*)(C + ((size_t)(i0 + ii) * IDIM + o0) * 5 + c4 * 4);
    float vals[4] = {f.x, f.y, f.z, f.w};
#pragma unroll
    for (int j = 0; j < 4; j++) {
      int p  = c4 * 4 + j;          // position within row = oo*5 + d
      int oo = p / 5, d = p - oo * 5;
      lds[(oo * 5 + d) * 64 + ii] = f2bf(vals[j]);
    }
  }
  __syncthreads();
  // write phase: coalesced ushort4 rows of Bt
#pragma unroll
  for (int r = 0; r < 16; r++) {
    int idx = r * 256 + t;
    int seg = idx >> 4, l16 = idx & 15;
    int oo = seg >> 2, d2 = seg & 3;
    int ii = l16 * 4;
    const unsigned short* src = &lds[(oo * 5 + d2 + 1) * 64 + ii];
    ushort4 u; u.x = src[0]; u.y = src[1]; u.z = src[2]; u.w = src[3];
    *(ushort4*)(Bt + (size_t)(o0 + oo) * KDIM + d2 * IDIM + i0 + ii) = u;
  }
  // bias partial: d == 0 slice
  if (t < 64) {
    float s = 0.f;
#pragma unroll
    for (int ii = 0; ii < 64; ii++) s += bf2f(lds[(t * 5 + 0) * 64 + ii]);
    atomicAdd(&bias[o0 + t], s);
  }
}

// ---------------------------------------------------------------------------
// Kernel 3: bf16 MFMA GEMM  out[m][n] = silu( A[m][:]·Bt[n][:] + bias[n] )
// BM=128, BN=64, BK=32, 256 threads (4 waves, 2x2), wave tile 64x32,
// mfma_f32_16x16x32_bf16, global_load_lds width-16 staging (m97 structure).
// ---------------------------------------------------------------------------
#define BM 128
#define BN 64
#define BK 32

__global__ __launch_bounds__(256, 2) void gemm_silu(
    const unsigned short* __restrict__ A,   // [BATCH][KDIM] bf16
    const unsigned short* __restrict__ Bt,  // [ODIM][KDIM]  bf16
    const float* __restrict__ bias,
    float* __restrict__ out) {              // [BATCH][ODIM] fp32
  __shared__ unsigned short As[BM * BK];    // 8 KB
  __shared__ unsigned short Bs[BN * BK];    // 4 KB
  int t = threadIdx.x;
  int lane = t & 63, w = t >> 6;
  int m0 = blockIdx.y * BM;
  int n0 = blockIdx.x * BN;
  int wm = (w >> 1) * 64;   // wave m offset in block tile
  int wn = (w & 1) * 32;    // wave n offset

  f32x4 acc[4][2];
#pragma unroll
  for (int i = 0; i < 4; i++)
#pragma unroll
    for (int j = 0; j < 2; j++) acc[i][j] = (f32x4){0.f, 0.f, 0.f, 0.f};

  // staging: lane l of wave w covers row (w*16 + l/4), 16B chunk (l%4)
  int srow = w * 16 + (lane >> 2);
  int scol = (lane & 3) * 8;                      // in elements
  const unsigned short* agp0 = A  + (size_t)(m0 + srow) * KDIM + scol;
  const unsigned short* agp1 = agp0 + (size_t)64 * KDIM;
  const unsigned short* bgp  = Bt + (size_t)(n0 + srow) * KDIM + scol;
  unsigned short* alp0 = &As[(w * 16) * BK];       // wave-uniform LDS bases
  unsigned short* alp1 = &As[(64 + w * 16) * BK];
  unsigned short* blp  = &Bs[(w * 16) * BK];

  // fragment read offsets (elements)
  int aoff = (wm + (lane & 15)) * BK + (lane >> 4) * 8;
  int boff = (wn + (lane & 15)) * BK + (lane >> 4) * 8;

  for (int k0 = 0; k0 < KDIM; k0 += BK) {
    load_lds16(agp0 + k0, alp0);
    load_lds16(agp1 + k0, alp1);
    load_lds16(bgp + k0, blp);
    __syncthreads();
    bf16x8 af[4], bfv[2];
#pragma unroll
    for (int i = 0; i < 4; i++) af[i] = *(const bf16x8*)&As[aoff + i * 16 * BK];
#pragma unroll
    for (int j = 0; j < 2; j++) bfv[j] = *(const bf16x8*)&Bs[boff + j * 16 * BK];
#pragma unroll
    for (int i = 0; i < 4; i++)
#pragma unroll
      for (int j = 0; j < 2; j++)
        acc[i][j] = __builtin_amdgcn_mfma_f32_16x16x32_bf16(af[i], bfv[j], acc[i][j], 0, 0, 0);
    __syncthreads();
  }

  // epilogue: D[m = (lane>>4)*4 + r][n = lane&15], + bias, silu, fp32 store
#pragma unroll
  for (int j = 0; j < 2; j++) {
    int col = n0 + wn + j * 16 + (lane & 15);
    float bc = bias[col];
#pragma unroll
    for (int i = 0; i < 4; i++) {
      int row = m0 + wm + i * 16 + (lane >> 4) * 4;
#pragma unroll
      for (int r = 0; r < 4; r++) {
        float y = acc[i][j][r] + bc;
        float sv = y / (1.0f + __expf(-y));
        out[(size_t)(row + r) * ODIM + col] = sv;
      }
    }
  }
}

// ---------------------------------------------------------------------------
extern "C" void kernel_launch(void* const* d_in, const int* in_sizes, int n_in,
                              void* d_out, int out_size, void* d_ws, size_t ws_size,
                              hipStream_t stream) {
  const float* x    = (const float*)d_in[0];
  const float* coef = (const float*)d_in[1];
  const float* lnw  = (const float*)d_in[2];
  const float* lnb  = (const float*)d_in[3];
  float* out = (float*)d_out;

  char* ws = (char*)d_ws;
  unsigned short* A  = (unsigned short*)ws;                                   // 32 MB
  unsigned short* Bt = (unsigned short*)(ws + (size_t)BATCH * KDIM * 2);      //  8 MB
  float* bias = (float*)(ws + (size_t)BATCH * KDIM * 2 + (size_t)ODIM * KDIM * 2);

  hipMemsetAsync(bias, 0, ODIM * sizeof(float), stream);
  prep_ln<<<BATCH, 256, 0, stream>>>(x, lnw, lnb, A);
  prep_coef<<<dim3(IDIM / 64, ODIM / 64), 256, 0, stream>>>(coef, Bt, bias);
  gemm_silu<<<dim3(ODIM / BN, BATCH / BM), 256, 0, stream>>>(A, Bt, bias, out);
}

// Round 2
// 163.670 us; speedup vs baseline: 1.0521x; 1.0521x over previous
//
#include <hip/hip_runtime.h>
#include <cstdint>
#include <cstddef>

#define BATCH 4096
#define IDIM 1024
#define ODIM 1024
#define KDIM 4096   // 4 * IDIM  (degrees 1..4; degree 0 folded into bias partials)

typedef __attribute__((ext_vector_type(8))) short bf16x8;
typedef __attribute__((ext_vector_type(4))) float f32x4;

__device__ __forceinline__ unsigned short f2bf(float f) {
  union { float f; unsigned int u; } v; v.f = f;
  unsigned int r = (v.u + 0x7FFFu + ((v.u >> 16) & 1u)) >> 16;  // RNE
  return (unsigned short)r;
}
__device__ __forceinline__ float bf2f(unsigned short u) {
  union { unsigned int u; float f; } v; v.u = ((unsigned int)u) << 16;
  return v.f;
}

__device__ __forceinline__ void load_lds16(const void* g, void* l) {
  __builtin_amdgcn_global_load_lds(
      (const __attribute__((address_space(1))) void*)g,
      (__attribute__((address_space(3))) void*)l, 16, 0, 0);
}

// ---------------------------------------------------------------------------
// Fused prep kernel.
//   blocks [0, 4096):      per-row LayerNorm + tanh + Chebyshev T1..T4 -> A bf16
//                          A[b][d2*1024 + i] = T_{d2+1}(h[b][i])
//   blocks [4096, 4352):   64i x 64o coeff tile transpose ->
//                          Bt[o][d2*1024+i] bf16  +  biasPart[ib][o] = sum_i C[i,o,0]
// No memset needed: biasPart fully written (16 i-blocks x 1024 o each).
// ---------------------------------------------------------------------------
__global__ __launch_bounds__(256) void prep(
    const float* __restrict__ x, const float* __restrict__ lnw,
    const float* __restrict__ lnb, const float* __restrict__ C,
    unsigned short* __restrict__ A, unsigned short* __restrict__ Bt,
    float* __restrict__ biasPart) {
  __shared__ __align__(16) unsigned short sm[64 * 5 * 64];  // 40 KB
  int bid = blockIdx.x;
  int t = threadIdx.x;

  if (bid < BATCH) {
    // ---- LayerNorm + tanh + Chebyshev ----
    float* rs = (float*)sm;        // 4 floats
    float* rq = ((float*)sm) + 4;  // 4 floats
    const float4 v = ((const float4*)(x + (size_t)bid * IDIM))[t];
    float s  = v.x + v.y + v.z + v.w;
    float s2 = v.x * v.x + v.y * v.y + v.z * v.z + v.w * v.w;
#pragma unroll
    for (int off = 32; off > 0; off >>= 1) {
      s  += __shfl_down(s, off);
      s2 += __shfl_down(s2, off);
    }
    int lane = t & 63, wv = t >> 6;
    if (lane == 0) { rs[wv] = s; rq[wv] = s2; }
    __syncthreads();
    float S1 = rs[0] + rs[1] + rs[2] + rs[3];
    float S2 = rq[0] + rq[1] + rq[2] + rq[3];
    float mean = S1 * (1.0f / IDIM);
    float var  = S2 * (1.0f / IDIM) - mean * mean;
    float rstd = rsqrtf(var + 1e-5f);

    const float4 w4 = ((const float4*)lnw)[t];
    const float4 b4 = ((const float4*)lnb)[t];
    float xs[4]  = {v.x, v.y, v.z, v.w};
    float ws4[4] = {w4.x, w4.y, w4.z, w4.w};
    float bs4[4] = {b4.x, b4.y, b4.z, b4.w};

    unsigned short u1[4], u2[4], u3[4], u4[4];
#pragma unroll
    for (int j = 0; j < 4; j++) {
      float h  = tanhf((xs[j] - mean) * rstd * ws4[j] + bs4[j]);
      float T2 = 2.0f * h * h - 1.0f;
      float T3 = 2.0f * h * T2 - h;
      float T4 = 2.0f * h * T3 - T2;
      u1[j] = f2bf(h); u2[j] = f2bf(T2); u3[j] = f2bf(T3); u4[j] = f2bf(T4);
    }
    size_t base = (size_t)bid * KDIM;
    *(ushort4*)(A + base + 0 * IDIM + t * 4) = *(ushort4*)u1;
    *(ushort4*)(A + base + 1 * IDIM + t * 4) = *(ushort4*)u2;
    *(ushort4*)(A + base + 2 * IDIM + t * 4) = *(ushort4*)u3;
    *(ushort4*)(A + base + 3 * IDIM + t * 4) = *(ushort4*)u4;
  } else {
    // ---- coeff transpose + bias partial ----
    int cb = bid - BATCH;
    int i0 = (cb & 15) * 64, o0 = (cb >> 4) * 64;
    // read phase: 64 rows x 320 floats contiguous
#pragma unroll
    for (int r = 0; r < 20; r++) {
      int idx = r * 256 + t;          // 0..5119 float4s
      int ii  = idx / 80;             // 80 float4 per i-row
      int c4  = idx - ii * 80;
      const float4 f = *(const float4*)(C + ((size_t)(i0 + ii) * ODIM + o0) * 5 + c4 * 4);
      float vals[4] = {f.x, f.y, f.z, f.w};
#pragma unroll
      for (int j = 0; j < 4; j++) {
        int p  = c4 * 4 + j;          // = oo*5 + d
        int oo = p / 5, d = p - oo * 5;
        sm[(oo * 5 + d) * 64 + ii] = f2bf(vals[j]);
      }
    }
    __syncthreads();
    // write phase: coalesced ushort4 rows of Bt
#pragma unroll
    for (int r = 0; r < 16; r++) {
      int idx = r * 256 + t;
      int seg = idx >> 4, l16 = idx & 15;
      int oo = seg >> 2, d2 = seg & 3;
      int ii = l16 * 4;
      const unsigned short* src = &sm[(oo * 5 + d2 + 1) * 64 + ii];
      ushort4 u; u.x = src[0]; u.y = src[1]; u.z = src[2]; u.w = src[3];
      *(ushort4*)(Bt + (size_t)(o0 + oo) * KDIM + d2 * IDIM + i0 + ii) = u;
    }
    // bias partial: d == 0 slice; rotate ii start to spread LDS banks
    if (t < 64) {
      float s = 0.f;
#pragma unroll
      for (int k = 0; k < 64; k++) {
        int ii = (t + k) & 63;
        s += bf2f(sm[(t * 5) * 64 + ii]);
      }
      biasPart[(size_t)(i0 >> 6) * ODIM + o0 + t] = s;
    }
  }
}

// ---------------------------------------------------------------------------
// bf16 MFMA GEMM  out[m][n] = silu( A[m][:]·Bt[n][:] + bias[n] )
// BM=128, BN=64, BK=64 (2 K-substeps per barrier -> 16 MFMA/wave/barrier),
// 256 threads (2x2 waves, wave tile 64x32), mfma_f32_16x16x32_bf16.
// LDS XOR swizzle: chunk c (16B) of row r stored at LDS chunk c^(r&7);
// staging picks the matching global chunk per lane (dest = base+lane*16 is
// fixed by global_load_lds), reads apply the same XOR -> conflict-free.
// Grid: x = m-block (fastest) so the 16 blocks sharing an A strip get ids
// congruent mod 8 -> same XCD -> A strip lives in exactly one L2.
// ---------------------------------------------------------------------------
#define BM 128
#define BN 64
#define BK 64

__global__ __launch_bounds__(256, 2) void gemm_silu(
    const unsigned short* __restrict__ A,        // [BATCH][KDIM] bf16
    const unsigned short* __restrict__ Bt,       // [ODIM][KDIM]  bf16
    const float* __restrict__ biasPart,          // [16][ODIM]
    float* __restrict__ out) {                   // [BATCH][ODIM] fp32
  __shared__ unsigned short As[BM * BK];         // 16 KB
  __shared__ unsigned short Bs[BN * BK];         // 8 KB
  int t = threadIdx.x;
  int lane = t & 63, w = t >> 6;
  int m0 = blockIdx.x * BM;    // m fastest
  int n0 = blockIdx.y * BN;
  int wm = (w >> 1) * 64;
  int wn = (w & 1) * 32;

  f32x4 acc[4][2];
#pragma unroll
  for (int i = 0; i < 4; i++)
#pragma unroll
    for (int j = 0; j < 2; j++) acc[i][j] = (f32x4){0.f, 0.f, 0.f, 0.f};

  // staging geometry: each wave-load covers 8 rows x 8 chunks (1 KB).
  // lane -> local row sr = lane>>3, LDS chunk cs = lane&7 which must hold
  // global chunk cs ^ (row&7) = (lane&7) ^ sr  (row&7 == sr; bases are %8==0).
  int sr = lane >> 3;
  int sc = ((lane & 7) ^ sr) * 8;  // element offset of the chunk this lane fetches
  const unsigned short* ag[4];
  unsigned short* al[4];
#pragma unroll
  for (int q = 0; q < 4; q++) {
    int row = q * 32 + w * 8;
    ag[q] = A + (size_t)(m0 + row + sr) * KDIM + sc;
    al[q] = &As[row * BK];
  }
  const unsigned short* bg[2];
  unsigned short* bl[2];
#pragma unroll
  for (int q = 0; q < 2; q++) {
    int row = q * 32 + w * 8;
    bg[q] = Bt + (size_t)(n0 + row + sr) * KDIM + sc;
    bl[q] = &Bs[row * BK];
  }

  // fragment read bases; row&7 == lane&7 for all fragment rows
  int arow = (wm + (lane & 15)) * BK;
  int brow = (wn + (lane & 15)) * BK;
  int x7 = lane & 7, hi = lane >> 4;

  for (int k0 = 0; k0 < KDIM; k0 += BK) {
#pragma unroll
    for (int q = 0; q < 4; q++) load_lds16(ag[q] + k0, al[q]);
#pragma unroll
    for (int q = 0; q < 2; q++) load_lds16(bg[q] + k0, bl[q]);
    __syncthreads();

    bf16x8 af[2][4], bfv[2][2];
#pragma unroll
    for (int kk = 0; kk < 2; kk++) {
      int co = ((kk * 4 + hi) ^ x7) * 8;   // de-swizzled chunk offset (elems)
#pragma unroll
      for (int i = 0; i < 4; i++) af[kk][i] = *(const bf16x8*)&As[arow + i * 16 * BK + co];
#pragma unroll
      for (int j = 0; j < 2; j++) bfv[kk][j] = *(const bf16x8*)&Bs[brow + j * 16 * BK + co];
    }
#pragma unroll
    for (int kk = 0; kk < 2; kk++)
#pragma unroll
      for (int i = 0; i < 4; i++)
#pragma unroll
        for (int j = 0; j < 2; j++)
          acc[i][j] = __builtin_amdgcn_mfma_f32_16x16x32_bf16(af[kk][i], bfv[kk][j], acc[i][j], 0, 0, 0);
    __syncthreads();
  }

  // epilogue: D[m = (lane>>4)*4 + r][n = lane&15]; bias = sum of 16 partials
#pragma unroll
  for (int j = 0; j < 2; j++) {
    int col = n0 + wn + j * 16 + (lane & 15);
    float bc = 0.f;
#pragma unroll
    for (int ib = 0; ib < 16; ib++) bc += biasPart[(size_t)ib * ODIM + col];
#pragma unroll
    for (int i = 0; i < 4; i++) {
      int row = m0 + wm + i * 16 + (lane >> 4) * 4;
#pragma unroll
      for (int r = 0; r < 4; r++) {
        float y = acc[i][j][r] + bc;
        float sv = y / (1.0f + __expf(-y));
        out[(size_t)(row + r) * ODIM + col] = sv;
      }
    }
  }
}

// ---------------------------------------------------------------------------
extern "C" void kernel_launch(void* const* d_in, const int* in_sizes, int n_in,
                              void* d_out, int out_size, void* d_ws, size_t ws_size,
                              hipStream_t stream) {
  const float* x    = (const float*)d_in[0];
  const float* coef = (const float*)d_in[1];
  const float* lnw  = (const float*)d_in[2];
  const float* lnb  = (const float*)d_in[3];
  float* out = (float*)d_out;

  char* ws = (char*)d_ws;
  unsigned short* A  = (unsigned short*)ws;                               // 32 MB
  unsigned short* Bt = (unsigned short*)(ws + (size_t)BATCH * KDIM * 2);  //  8 MB
  float* biasPart = (float*)(ws + (size_t)BATCH * KDIM * 2 + (size_t)ODIM * KDIM * 2);  // 64 KB

  prep<<<BATCH + 256, 256, 0, stream>>>(x, lnw, lnb, coef, A, Bt, biasPart);
  gemm_silu<<<dim3(BATCH / BM, ODIM / BN), 256, 0, stream>>>(A, Bt, biasPart, out);
}

// Round 3
// 138.882 us; speedup vs baseline: 1.2399x; 1.1785x over previous
//
#include <hip/hip_runtime.h>
#include <cstdint>
#include <cstddef>

#define BATCH 4096
#define IDIM 1024
#define ODIM 1024
#define KDIM 4096   // 4 * IDIM  (degrees 1..4; degree 0 folded into bias partials)
#define KHALF 2048  // split-K factor 2

typedef __attribute__((ext_vector_type(8))) short bf16x8;
typedef __attribute__((ext_vector_type(4))) float f32x4;

__device__ __forceinline__ unsigned short f2bf(float f) {
  union { float f; unsigned int u; } v; v.f = f;
  unsigned int r = (v.u + 0x7FFFu + ((v.u >> 16) & 1u)) >> 16;  // RNE
  return (unsigned short)r;
}
__device__ __forceinline__ float bf2f(unsigned short u) {
  union { unsigned int u; float f; } v; v.u = ((unsigned int)u) << 16;
  return v.f;
}

__device__ __forceinline__ void load_lds16(const void* g, void* l) {
  __builtin_amdgcn_global_load_lds(
      (const __attribute__((address_space(1))) void*)g,
      (__attribute__((address_space(3))) void*)l, 16, 0, 0);
}

// transpose LDS swizzle: short index for logical (p, ii), p = oo*5+d row.
// granularity-4 XOR keeps ushort4 alignment; writes 4-way max, reads ~free.
__device__ __forceinline__ int sidx(int p, int ii) {
  return p * 64 + ((ii + 4 * (p & 15)) & 63);
}

// ---------------------------------------------------------------------------
// Fused prep kernel.
//   blocks [0, 4096):      LayerNorm + tanh + Chebyshev T1..T4 -> A bf16
//   blocks [4096, 4352):   64i x 64o coeff tile transpose -> Bt bf16
//                          + biasPart[ib][o] = sum_i C[i,o,0]
// ---------------------------------------------------------------------------
__global__ __launch_bounds__(256) void prep(
    const float* __restrict__ x, const float* __restrict__ lnw,
    const float* __restrict__ lnb, const float* __restrict__ C,
    unsigned short* __restrict__ A, unsigned short* __restrict__ Bt,
    float* __restrict__ biasPart) {
  __shared__ __align__(16) unsigned short sm[64 * 5 * 64];  // 40 KB
  int bid = blockIdx.x;
  int t = threadIdx.x;

  if (bid < BATCH) {
    float* rs = (float*)sm;
    float* rq = ((float*)sm) + 4;
    const float4 v = ((const float4*)(x + (size_t)bid * IDIM))[t];
    float s  = v.x + v.y + v.z + v.w;
    float s2 = v.x * v.x + v.y * v.y + v.z * v.z + v.w * v.w;
#pragma unroll
    for (int off = 32; off > 0; off >>= 1) {
      s  += __shfl_down(s, off);
      s2 += __shfl_down(s2, off);
    }
    int lane = t & 63, wv = t >> 6;
    if (lane == 0) { rs[wv] = s; rq[wv] = s2; }
    __syncthreads();
    float S1 = rs[0] + rs[1] + rs[2] + rs[3];
    float S2 = rq[0] + rq[1] + rq[2] + rq[3];
    float mean = S1 * (1.0f / IDIM);
    float var  = S2 * (1.0f / IDIM) - mean * mean;
    float rstd = rsqrtf(var + 1e-5f);

    const float4 w4 = ((const float4*)lnw)[t];
    const float4 b4 = ((const float4*)lnb)[t];
    float xs[4]  = {v.x, v.y, v.z, v.w};
    float ws4[4] = {w4.x, w4.y, w4.z, w4.w};
    float bs4[4] = {b4.x, b4.y, b4.z, b4.w};

    unsigned short u1[4], u2[4], u3[4], u4[4];
#pragma unroll
    for (int j = 0; j < 4; j++) {
      float h  = tanhf((xs[j] - mean) * rstd * ws4[j] + bs4[j]);
      float T2 = 2.0f * h * h - 1.0f;
      float T3 = 2.0f * h * T2 - h;
      float T4 = 2.0f * h * T3 - T2;
      u1[j] = f2bf(h); u2[j] = f2bf(T2); u3[j] = f2bf(T3); u4[j] = f2bf(T4);
    }
    size_t base = (size_t)bid * KDIM;
    *(ushort4*)(A + base + 0 * IDIM + t * 4) = *(ushort4*)u1;
    *(ushort4*)(A + base + 1 * IDIM + t * 4) = *(ushort4*)u2;
    *(ushort4*)(A + base + 2 * IDIM + t * 4) = *(ushort4*)u3;
    *(ushort4*)(A + base + 3 * IDIM + t * 4) = *(ushort4*)u4;
  } else {
    int cb = bid - BATCH;
    int i0 = (cb & 15) * 64, o0 = (cb >> 4) * 64;
#pragma unroll
    for (int r = 0; r < 20; r++) {
      int idx = r * 256 + t;          // 0..5119 float4s
      int ii  = idx / 80;             // 80 float4 per i-row
      int c4  = idx - ii * 80;
      const float4 f = *(const float4*)(C + ((size_t)(i0 + ii) * ODIM + o0) * 5 + c4 * 4);
      float vals[4] = {f.x, f.y, f.z, f.w};
#pragma unroll
      for (int j = 0; j < 4; j++) {
        int p = c4 * 4 + j;           // = oo*5 + d
        sm[sidx(p, ii)] = f2bf(vals[j]);
      }
    }
    __syncthreads();
#pragma unroll
    for (int r = 0; r < 16; r++) {
      int idx = r * 256 + t;
      int seg = idx >> 4, l16 = idx & 15;
      int oo = seg >> 2, d2 = seg & 3;
      int p = oo * 5 + d2 + 1;
      const unsigned short* src = &sm[sidx(p, l16 * 4)];
      ushort4 u = *(const ushort4*)src;
      *(ushort4*)(Bt + (size_t)(o0 + oo) * KDIM + d2 * IDIM + i0 + l16 * 4) = u;
    }
    if (t < 64) {
      float s = 0.f;
      int p = t * 5;
#pragma unroll
      for (int ii = 0; ii < 64; ii++) s += bf2f(sm[sidx(p, ii)]);
      biasPart[(size_t)(i0 >> 6) * ODIM + o0 + t] = s;
    }
  }
}

// ---------------------------------------------------------------------------
// bf16 MFMA GEMM, split-K x2.  128x128 tile, 2x2 waves of 64x64 (4x4 acc),
// BK=64, XOR-swizzled LDS (conflict-free), global_load_lds width-16 staging.
// z=0 writes raw sums + bias into out0; z=1 writes raw sums into part1.
// Grid x = m-block fastest: blocks sharing an A strip land on one XCD.
// ---------------------------------------------------------------------------
#define BM 128
#define BN 128
#define BK 64

__global__ __launch_bounds__(256, 2) void gemm_part(
    const unsigned short* __restrict__ A,        // [BATCH][KDIM] bf16
    const unsigned short* __restrict__ Bt,       // [ODIM][KDIM]  bf16
    const float* __restrict__ biasPart,          // [16][ODIM]
    float* __restrict__ out0,                    // z=0 partial (+bias)
    float* __restrict__ part1) {                 // z=1 partial
  __shared__ unsigned short As[BM * BK];         // 16 KB
  __shared__ unsigned short Bs[BN * BK];         // 16 KB
  int t = threadIdx.x;
  int lane = t & 63, w = t >> 6;
  int m0 = blockIdx.x * BM;
  int n0 = blockIdx.y * BN;
  size_t kbase = (size_t)blockIdx.z * KHALF;

  f32x4 acc[4][4];
#pragma unroll
  for (int i = 0; i < 4; i++)
#pragma unroll
    for (int j = 0; j < 4; j++) acc[i][j] = (f32x4){0.f, 0.f, 0.f, 0.f};

  int wm = (w >> 1) * 64;
  int wn = (w & 1) * 64;

  // staging: each wave-load = 8 rows x 8 chunks (1 KB); 4 A + 4 B per thread
  int sr = lane >> 3;
  int sc = ((lane & 7) ^ sr) * 8;
  const unsigned short* ag[4]; unsigned short* al[4];
  const unsigned short* bg[4]; unsigned short* bl[4];
#pragma unroll
  for (int q = 0; q < 4; q++) {
    int row = w * 8 + q * 32;
    ag[q] = A  + (size_t)(m0 + row + sr) * KDIM + kbase + sc;
    al[q] = &As[row * BK];
    bg[q] = Bt + (size_t)(n0 + row + sr) * KDIM + kbase + sc;
    bl[q] = &Bs[row * BK];
  }

  int arow = (wm + (lane & 15)) * BK;
  int brow = (wn + (lane & 15)) * BK;
  int x7 = lane & 7, hi = lane >> 4;

  for (int k0 = 0; k0 < KHALF; k0 += BK) {
#pragma unroll
    for (int q = 0; q < 4; q++) load_lds16(ag[q] + k0, al[q]);
#pragma unroll
    for (int q = 0; q < 4; q++) load_lds16(bg[q] + k0, bl[q]);
    __syncthreads();
#pragma unroll
    for (int kk = 0; kk < 2; kk++) {
      int co = ((kk * 4 + hi) ^ x7) * 8;
      bf16x8 af[4], bfv[4];
#pragma unroll
      for (int i = 0; i < 4; i++) af[i]  = *(const bf16x8*)&As[arow + i * 16 * BK + co];
#pragma unroll
      for (int j = 0; j < 4; j++) bfv[j] = *(const bf16x8*)&Bs[brow + j * 16 * BK + co];
#pragma unroll
      for (int i = 0; i < 4; i++)
#pragma unroll
        for (int j = 0; j < 4; j++)
          acc[i][j] = __builtin_amdgcn_mfma_f32_16x16x32_bf16(af[i], bfv[j], acc[i][j], 0, 0, 0);
    }
    __syncthreads();
  }

  float* dst = (blockIdx.z == 0) ? out0 : part1;
  bool addb = (blockIdx.z == 0);
#pragma unroll
  for (int j = 0; j < 4; j++) {
    int col = n0 + wn + j * 16 + (lane & 15);
    float bc = 0.f;
    if (addb) {
#pragma unroll
      for (int ib = 0; ib < 16; ib++) bc += biasPart[(size_t)ib * ODIM + col];
    }
#pragma unroll
    for (int i = 0; i < 4; i++) {
      int row = m0 + wm + i * 16 + hi * 4;
#pragma unroll
      for (int r = 0; r < 4; r++)
        dst[(size_t)(row + r) * ODIM + col] = acc[i][j][r] + bc;
    }
  }
}

// ---------------------------------------------------------------------------
// reduce: out = silu(out + part1)
// ---------------------------------------------------------------------------
__global__ __launch_bounds__(256) void reduce_silu(
    float* __restrict__ out, const float* __restrict__ part1) {
  int idx = blockIdx.x * 256 + threadIdx.x;
  float4 a = ((const float4*)out)[idx];
  float4 b = ((const float4*)part1)[idx];
  float y0 = a.x + b.x, y1 = a.y + b.y, y2 = a.z + b.z, y3 = a.w + b.w;
  float4 o;
  o.x = y0 / (1.0f + __expf(-y0));
  o.y = y1 / (1.0f + __expf(-y1));
  o.z = y2 / (1.0f + __expf(-y2));
  o.w = y3 / (1.0f + __expf(-y3));
  ((float4*)out)[idx] = o;
}

// ---------------------------------------------------------------------------
extern "C" void kernel_launch(void* const* d_in, const int* in_sizes, int n_in,
                              void* d_out, int out_size, void* d_ws, size_t ws_size,
                              hipStream_t stream) {
  const float* x    = (const float*)d_in[0];
  const float* coef = (const float*)d_in[1];
  const float* lnw  = (const float*)d_in[2];
  const float* lnb  = (const float*)d_in[3];
  float* out = (float*)d_out;

  char* ws = (char*)d_ws;
  unsigned short* A  = (unsigned short*)ws;                               // 32 MB
  unsigned short* Bt = (unsigned short*)(ws + (size_t)BATCH * KDIM * 2);  //  8 MB
  char* p = ws + (size_t)BATCH * KDIM * 2 + (size_t)ODIM * KDIM * 2;
  float* biasPart = (float*)p;                                            // 64 KB
  float* part1 = (float*)(p + 16 * ODIM * sizeof(float));                 // 16 MB

  prep<<<BATCH + 256, 256, 0, stream>>>(x, lnw, lnb, coef, A, Bt, biasPart);
  gemm_part<<<dim3(BATCH / BM, ODIM / BN, 2), 256, 0, stream>>>(A, Bt, biasPart, out, part1);
  reduce_silu<<<(BATCH * ODIM) / (256 * 4), 256, 0, stream>>>(out, part1);
}

// Round 4
// 138.437 us; speedup vs baseline: 1.2439x; 1.0032x over previous
//
#include <hip/hip_runtime.h>
#include <cstdint>
#include <cstddef>

#define BATCH 4096
#define IDIM 1024
#define ODIM 1024
#define KDIM 4096   // 4 * IDIM  (degrees 1..4; degree 0 folded into bias partials)
#define KHALF 2048  // split-K factor 2

typedef __attribute__((ext_vector_type(8))) short bf16x8;
typedef __attribute__((ext_vector_type(4))) float f32x4;

__device__ __forceinline__ unsigned short f2bf(float f) {
  union { float f; unsigned int u; } v; v.f = f;
  unsigned int r = (v.u + 0x7FFFu + ((v.u >> 16) & 1u)) >> 16;  // RNE
  return (unsigned short)r;
}
__device__ __forceinline__ float bf2f(unsigned short u) {
  union { unsigned int u; float f; } v; v.u = ((unsigned int)u) << 16;
  return v.f;
}

__device__ __forceinline__ void load_lds16(const void* g, void* l) {
  __builtin_amdgcn_global_load_lds(
      (const __attribute__((address_space(1))) void*)g,
      (__attribute__((address_space(3))) void*)l, 16, 0, 0);
}

// transpose LDS swizzle: short index for logical (p, ii), p = oo*5+d row.
__device__ __forceinline__ int sidx(int p, int ii) {
  return p * 64 + ((ii + 4 * (p & 15)) & 63);
}

// ---------------------------------------------------------------------------
// Fused prep kernel (unchanged from round 3).
//   blocks [0, 4096):      LayerNorm + tanh + Chebyshev T1..T4 -> A bf16
//   blocks [4096, 4352):   64i x 64o coeff tile transpose -> Bt bf16
//                          + biasPart[ib][o] = sum_i C[i,o,0]
// ---------------------------------------------------------------------------
__global__ __launch_bounds__(256) void prep(
    const float* __restrict__ x, const float* __restrict__ lnw,
    const float* __restrict__ lnb, const float* __restrict__ C,
    unsigned short* __restrict__ A, unsigned short* __restrict__ Bt,
    float* __restrict__ biasPart) {
  __shared__ __align__(16) unsigned short sm[64 * 5 * 64];  // 40 KB
  int bid = blockIdx.x;
  int t = threadIdx.x;

  if (bid < BATCH) {
    float* rs = (float*)sm;
    float* rq = ((float*)sm) + 4;
    const float4 v = ((const float4*)(x + (size_t)bid * IDIM))[t];
    float s  = v.x + v.y + v.z + v.w;
    float s2 = v.x * v.x + v.y * v.y + v.z * v.z + v.w * v.w;
#pragma unroll
    for (int off = 32; off > 0; off >>= 1) {
      s  += __shfl_down(s, off);
      s2 += __shfl_down(s2, off);
    }
    int lane = t & 63, wv = t >> 6;
    if (lane == 0) { rs[wv] = s; rq[wv] = s2; }
    __syncthreads();
    float S1 = rs[0] + rs[1] + rs[2] + rs[3];
    float S2 = rq[0] + rq[1] + rq[2] + rq[3];
    float mean = S1 * (1.0f / IDIM);
    float var  = S2 * (1.0f / IDIM) - mean * mean;
    float rstd = rsqrtf(var + 1e-5f);

    const float4 w4 = ((const float4*)lnw)[t];
    const float4 b4 = ((const float4*)lnb)[t];
    float xs[4]  = {v.x, v.y, v.z, v.w};
    float ws4[4] = {w4.x, w4.y, w4.z, w4.w};
    float bs4[4] = {b4.x, b4.y, b4.z, b4.w};

    unsigned short u1[4], u2[4], u3[4], u4[4];
#pragma unroll
    for (int j = 0; j < 4; j++) {
      float h  = tanhf((xs[j] - mean) * rstd * ws4[j] + bs4[j]);
      float T2 = 2.0f * h * h - 1.0f;
      float T3 = 2.0f * h * T2 - h;
      float T4 = 2.0f * h * T3 - T2;
      u1[j] = f2bf(h); u2[j] = f2bf(T2); u3[j] = f2bf(T3); u4[j] = f2bf(T4);
    }
    size_t base = (size_t)bid * KDIM;
    *(ushort4*)(A + base + 0 * IDIM + t * 4) = *(ushort4*)u1;
    *(ushort4*)(A + base + 1 * IDIM + t * 4) = *(ushort4*)u2;
    *(ushort4*)(A + base + 2 * IDIM + t * 4) = *(ushort4*)u3;
    *(ushort4*)(A + base + 3 * IDIM + t * 4) = *(ushort4*)u4;
  } else {
    int cb = bid - BATCH;
    int i0 = (cb & 15) * 64, o0 = (cb >> 4) * 64;
#pragma unroll
    for (int r = 0; r < 20; r++) {
      int idx = r * 256 + t;          // 0..5119 float4s
      int ii  = idx / 80;             // 80 float4 per i-row
      int c4  = idx - ii * 80;
      const float4 f = *(const float4*)(C + ((size_t)(i0 + ii) * ODIM + o0) * 5 + c4 * 4);
      float vals[4] = {f.x, f.y, f.z, f.w};
#pragma unroll
      for (int j = 0; j < 4; j++) {
        int p = c4 * 4 + j;           // = oo*5 + d
        sm[sidx(p, ii)] = f2bf(vals[j]);
      }
    }
    __syncthreads();
#pragma unroll
    for (int r = 0; r < 16; r++) {
      int idx = r * 256 + t;
      int seg = idx >> 4, l16 = idx & 15;
      int oo = seg >> 2, d2 = seg & 3;
      int p = oo * 5 + d2 + 1;
      const unsigned short* src = &sm[sidx(p, l16 * 4)];
      ushort4 u = *(const ushort4*)src;
      *(ushort4*)(Bt + (size_t)(o0 + oo) * KDIM + d2 * IDIM + i0 + l16 * 4) = u;
    }
    if (t < 64) {
      float s = 0.f;
      int p = t * 5;
#pragma unroll
      for (int ii = 0; ii < 64; ii++) s += bf2f(sm[sidx(p, ii)]);
      biasPart[(size_t)(i0 >> 6) * ODIM + o0 + t] = s;
    }
  }
}

// ---------------------------------------------------------------------------
// bf16 MFMA GEMM, split-K x2, single-barrier DOUBLE-BUFFERED prefetch.
// 128x128 tile, 2x2 waves of 64x64 (4x4 acc), BK=64, XOR-swizzled LDS.
// Loop body: sync -> issue prefetch(buf^1) -> compute(buf). The vmcnt(0)
// drain at each barrier now waits on loads that had a full compute phase
// in flight, instead of zero (round-3's 2-barrier shape).
// ---------------------------------------------------------------------------
#define BM 128
#define BN 128
#define BK 64
#define NIT (KHALF / BK)   // 32

__global__ __launch_bounds__(256, 2) void gemm_part(
    const unsigned short* __restrict__ A,        // [BATCH][KDIM] bf16
    const unsigned short* __restrict__ Bt,       // [ODIM][KDIM]  bf16
    const float* __restrict__ biasPart,          // [16][ODIM]
    float* __restrict__ out0,                    // z=0 partial (+bias)
    float* __restrict__ part1) {                 // z=1 partial
  __shared__ unsigned short As[2 * BM * BK];     // 2 x 16 KB
  __shared__ unsigned short Bs[2 * BN * BK];     // 2 x 16 KB  (64 KB total)
  int t = threadIdx.x;
  int lane = t & 63, w = t >> 6;
  int m0 = blockIdx.x * BM;    // m fastest -> A strip stays on one XCD
  int n0 = blockIdx.y * BN;
  size_t kbase = (size_t)blockIdx.z * KHALF;

  f32x4 acc[4][4];
#pragma unroll
  for (int i = 0; i < 4; i++)
#pragma unroll
    for (int j = 0; j < 4; j++) acc[i][j] = (f32x4){0.f, 0.f, 0.f, 0.f};

  int wm = (w >> 1) * 64;
  int wn = (w & 1) * 64;

  // staging: each wave-load = 8 rows x 8 chunks (1 KB); XOR chunk swizzle
  int sr = lane >> 3;
  int sc = ((lane & 7) ^ sr) * 8;
  const unsigned short* ag[4]; unsigned short* al[4];
  const unsigned short* bg[4]; unsigned short* bl[4];
#pragma unroll
  for (int q = 0; q < 4; q++) {
    int row = w * 8 + q * 32;
    ag[q] = A  + (size_t)(m0 + row + sr) * KDIM + kbase + sc;
    al[q] = &As[row * BK];
    bg[q] = Bt + (size_t)(n0 + row + sr) * KDIM + kbase + sc;
    bl[q] = &Bs[row * BK];
  }

  int arow = (wm + (lane & 15)) * BK;
  int brow = (wn + (lane & 15)) * BK;
  int x7 = lane & 7, hi = lane >> 4;

#define ISSUE(buf, kk0)                                                     \
  do {                                                                      \
    int _k = (kk0);                                                         \
    _Pragma("unroll")                                                       \
    for (int q = 0; q < 4; q++) load_lds16(ag[q] + _k, al[q] + (buf) * (BM * BK)); \
    _Pragma("unroll")                                                       \
    for (int q = 0; q < 4; q++) load_lds16(bg[q] + _k, bl[q] + (buf) * (BN * BK)); \
  } while (0)

#define COMPUTE(buf)                                                        \
  do {                                                                      \
    _Pragma("unroll")                                                       \
    for (int kk = 0; kk < 2; kk++) {                                        \
      int co = ((kk * 4 + hi) ^ x7) * 8;                                    \
      bf16x8 af[4], bfv[4];                                                 \
      _Pragma("unroll")                                                     \
      for (int i = 0; i < 4; i++)                                           \
        af[i]  = *(const bf16x8*)&As[(buf) * (BM * BK) + arow + i * 16 * BK + co]; \
      _Pragma("unroll")                                                     \
      for (int j = 0; j < 4; j++)                                           \
        bfv[j] = *(const bf16x8*)&Bs[(buf) * (BN * BK) + brow + j * 16 * BK + co]; \
      _Pragma("unroll")                                                     \
      for (int i = 0; i < 4; i++)                                           \
        _Pragma("unroll")                                                   \
        for (int j = 0; j < 4; j++)                                         \
          acc[i][j] = __builtin_amdgcn_mfma_f32_16x16x32_bf16(af[i], bfv[j], acc[i][j], 0, 0, 0); \
    }                                                                       \
  } while (0)

  // prologue: fill buffer 0
  ISSUE(0, 0);
  // main loop, unrolled x2 so buffer indices are compile-time
  for (int it = 0; it < NIT; it += 2) {
    __syncthreads();                       // drains buf0 prefetch (1 compute in flight)
    if (it + 1 < NIT) ISSUE(1, (it + 1) * BK);
    COMPUTE(0);
    __syncthreads();                       // drains buf1 prefetch
    if (it + 2 < NIT) ISSUE(0, (it + 2) * BK);
    COMPUTE(1);
  }

  float* dst = (blockIdx.z == 0) ? out0 : part1;
  bool addb = (blockIdx.z == 0);
#pragma unroll
  for (int j = 0; j < 4; j++) {
    int col = n0 + wn + j * 16 + (lane & 15);
    float bc = 0.f;
    if (addb) {
#pragma unroll
      for (int ib = 0; ib < 16; ib++) bc += biasPart[(size_t)ib * ODIM + col];
    }
#pragma unroll
    for (int i = 0; i < 4; i++) {
      int row = m0 + wm + i * 16 + hi * 4;
#pragma unroll
      for (int r = 0; r < 4; r++)
        dst[(size_t)(row + r) * ODIM + col] = acc[i][j][r] + bc;
    }
  }
}

// ---------------------------------------------------------------------------
// reduce: out = silu(out + part1)
// ---------------------------------------------------------------------------
__global__ __launch_bounds__(256) void reduce_silu(
    float* __restrict__ out, const float* __restrict__ part1) {
  int idx = blockIdx.x * 256 + threadIdx.x;
  float4 a = ((const float4*)out)[idx];
  float4 b = ((const float4*)part1)[idx];
  float y0 = a.x + b.x, y1 = a.y + b.y, y2 = a.z + b.z, y3 = a.w + b.w;
  float4 o;
  o.x = y0 / (1.0f + __expf(-y0));
  o.y = y1 / (1.0f + __expf(-y1));
  o.z = y2 / (1.0f + __expf(-y2));
  o.w = y3 / (1.0f + __expf(-y3));
  ((float4*)out)[idx] = o;
}

// ---------------------------------------------------------------------------
extern "C" void kernel_launch(void* const* d_in, const int* in_sizes, int n_in,
                              void* d_out, int out_size, void* d_ws, size_t ws_size,
                              hipStream_t stream) {
  const float* x    = (const float*)d_in[0];
  const float* coef = (const float*)d_in[1];
  const float* lnw  = (const float*)d_in[2];
  const float* lnb  = (const float*)d_in[3];
  float* out = (float*)d_out;

  char* ws = (char*)d_ws;
  unsigned short* A  = (unsigned short*)ws;                               // 32 MB
  unsigned short* Bt = (unsigned short*)(ws + (size_t)BATCH * KDIM * 2);  //  8 MB
  char* p = ws + (size_t)BATCH * KDIM * 2 + (size_t)ODIM * KDIM * 2;
  float* biasPart = (float*)p;                                            // 64 KB
  float* part1 = (float*)(p + 16 * ODIM * sizeof(float));                 // 16 MB

  prep<<<BATCH + 256, 256, 0, stream>>>(x, lnw, lnb, coef, A, Bt, biasPart);
  gemm_part<<<dim3(BATCH / BM, ODIM / BN, 2), 256, 0, stream>>>(A, Bt, biasPart, out, part1);
  reduce_silu<<<(BATCH * ODIM) / (256 * 4), 256, 0, stream>>>(out, part1);
}